// Round 1
// baseline (139.774 us; speedup 1.0000x reference)
//
#include <hip/hip_runtime.h>
#include <hip/hip_bf16.h>

// AttentionNTKChoiceModel — f32 baseline.
// Shapes: B=32, L=512, D=128, H=8, D0=D2=32.
// Key algebraic simplification: out is only used via dot(out[b,l,h,:], w[h,:]),
// so fold w into the V projection:  u[h,:] = sum_d w[h,d]*W3[h*32+d,:]/sqrt(8)
//   Vw[b,m,h] = X[b,m,:] . u[h,:]
//   v[b,l]    = sum_h sum_m softmax_m(QK^T/sqrt(32) + keymask)[l,m] * Vw[b,m,h]
// Query-side masking is applied only in the final softmax (rows with invalid q
// are overwritten with NEG before the final softmax, matching the reference).
//
// ASSUMPTION: boolean `mask` input arrives as int32 (harness "integer -> const int*").
//
// ws layout (floats): u[8*128] | Y[16384*520] | vws[32*8*512]
//   Y cols: 0..255 = Q (h*32+d), 256..511 = K, 512..519 = Vw[h]

#define NEG (-10000.0f)
#define YC 520

__global__ void fold_w_kernel(const float* __restrict__ W3,
                              const float* __restrict__ w,
                              float* __restrict__ u) {
  const int h = blockIdx.x, k = threadIdx.x;  // grid 8, block 128
  float acc = 0.f;
#pragma unroll
  for (int d = 0; d < 32; ++d)
    acc += W3[(h * 32 + d) * 128 + k] * w[h * 32 + d];
  u[h * 128 + k] = acc * 0.3535533905932738f;  // includes 1/sqrt(8)
}

// Y[16384][520] = X[16384][128] @ Wcat^T ; Wcat rows: W1(0..255), W2(256..511), u(512..519)
__global__ __launch_bounds__(256) void proj_kernel(
    const float* __restrict__ X, const float* __restrict__ W1,
    const float* __restrict__ W2, const float* __restrict__ u,
    float* __restrict__ Y) {
  __shared__ float Xs[64][132];
  __shared__ float Ws[64][132];
  const int t = threadIdx.x;
  const int row0 = blockIdx.x * 64;
  const int col0 = blockIdx.y * 64;
  {
    const int r = t >> 5;          // 0..7
    const int c4 = (t & 31) * 4;   // 0..124
#pragma unroll
    for (int p = 0; p < 8; ++p) {
      const int rr = p * 8 + r;
      *(float4*)&Xs[rr][c4] = *(const float4*)&X[(size_t)(row0 + rr) * 128 + c4];
      const int j = col0 + rr;
      float4 wv = make_float4(0.f, 0.f, 0.f, 0.f);
      if (j < 256)      wv = *(const float4*)&W1[(size_t)j * 128 + c4];
      else if (j < 512) wv = *(const float4*)&W2[(size_t)(j - 256) * 128 + c4];
      else if (j < YC)  wv = *(const float4*)&u[(size_t)(j - 512) * 128 + c4];
      *(float4*)&Ws[rr][c4] = wv;
    }
  }
  __syncthreads();
  // interleaved assignment: row = i*16+ty, col = j*16+tx  (LDS banks spread)
  const int ty = t >> 4;   // 0..15
  const int tx = t & 15;   // 0..15
  float acc[4][4] = {};
  for (int k = 0; k < 128; ++k) {
    float a[4], bv[4];
#pragma unroll
    for (int i = 0; i < 4; ++i) a[i] = Xs[i * 16 + ty][k];
#pragma unroll
    for (int j = 0; j < 4; ++j) bv[j] = Ws[j * 16 + tx][k];
#pragma unroll
    for (int i = 0; i < 4; ++i)
#pragma unroll
      for (int j = 0; j < 4; ++j)
        acc[i][j] = fmaf(a[i], bv[j], acc[i][j]);
  }
#pragma unroll
  for (int i = 0; i < 4; ++i) {
    const int row = row0 + i * 16 + ty;
#pragma unroll
    for (int j = 0; j < 4; ++j) {
      const int col = col0 + j * 16 + tx;
      if (col < YC) Y[(size_t)row * YC + col] = acc[i][j];
    }
  }
}

// One block per (qtile of 64 queries, h, b). 256 threads.
// Thread (tq=t/32, tk=t&31) owns 8 query rows (tq*8+i) x 8 keys (j*32+tk) per 256-key chunk.
__global__ __launch_bounds__(256) void attn_kernel(
    const float* __restrict__ Y, const int* __restrict__ mask,
    float* __restrict__ vws) {
  __shared__ float Qs[64][33];
  __shared__ float Ks[256][33];
  __shared__ float Vws[256];
  __shared__ float biasS[256];
  const int t = threadIdx.x;
  const int qt = blockIdx.x, h = blockIdx.y, b = blockIdx.z;
  const float scale = 0.17677669529663687f;  // 1/sqrt(32)
  {
    const int r = t >> 3, c4 = (t & 7) * 4;
#pragma unroll
    for (int p = 0; p < 2; ++p) {
      const int q = p * 32 + r;
      *(float4*)&Qs[q][c4] =
          *(const float4*)&Y[(size_t)(b * 512 + qt * 64 + q) * YC + h * 32 + c4];
    }
  }
  const int tq = t >> 5, tk = t & 31;
  float m[8], lsum[8], val[8];
#pragma unroll
  for (int i = 0; i < 8; ++i) { m[i] = -3.0e38f; lsum[i] = 0.f; val[i] = 0.f; }

  for (int ch = 0; ch < 2; ++ch) {
    const int m0 = ch * 256;
    __syncthreads();  // protects Qs (ch=0) and previous-chunk Ks reads (ch=1)
    {
      const int r = t >> 3, c4 = (t & 7) * 4;
#pragma unroll
      for (int p = 0; p < 8; ++p) {
        const int mm = p * 32 + r;
        *(float4*)&Ks[mm][c4] =
            *(const float4*)&Y[(size_t)(b * 512 + m0 + mm) * YC + 256 + h * 32 + c4];
      }
      Vws[t] = Y[(size_t)(b * 512 + m0 + t) * YC + 512 + h];
      biasS[t] = mask[b * 512 + m0 + t] ? 0.f : NEG;
    }
    __syncthreads();
    float acc[8][8] = {};
    for (int k = 0; k < 32; ++k) {
      float a[8], bv[8];
#pragma unroll
      for (int i = 0; i < 8; ++i) a[i] = Qs[tq * 8 + i][k];
#pragma unroll
      for (int j = 0; j < 8; ++j) bv[j] = Ks[j * 32 + tk][k];
#pragma unroll
      for (int i = 0; i < 8; ++i)
#pragma unroll
        for (int j = 0; j < 8; ++j)
          acc[i][j] = fmaf(a[i], bv[j], acc[i][j]);
    }
#pragma unroll
    for (int i = 0; i < 8; ++i) {
      float s[8];
      float cm = -3.0e38f;
#pragma unroll
      for (int j = 0; j < 8; ++j) {
        s[j] = fmaf(acc[i][j], scale, biasS[j * 32 + tk]);
        cm = fmaxf(cm, s[j]);
      }
#pragma unroll
      for (int off = 16; off >= 1; off >>= 1)
        cm = fmaxf(cm, __shfl_xor(cm, off));
      const float nm = fmaxf(m[i], cm);
      const float f = __expf(m[i] - nm);  // exp(-inf)=0 on first chunk
      lsum[i] *= f; val[i] *= f; m[i] = nm;
#pragma unroll
      for (int j = 0; j < 8; ++j) {
        const float p = __expf(s[j] - nm);
        lsum[i] += p;
        val[i] = fmaf(p, Vws[j * 32 + tk], val[i]);
      }
    }
  }
#pragma unroll
  for (int i = 0; i < 8; ++i) {
#pragma unroll
    for (int off = 16; off >= 1; off >>= 1) {
      lsum[i] += __shfl_xor(lsum[i], off);
      val[i]  += __shfl_xor(val[i], off);
    }
  }
  if (tk == 0) {
#pragma unroll
    for (int i = 0; i < 8; ++i)
      vws[(size_t)(b * 8 + h) * 512 + qt * 64 + tq * 8 + i] = val[i] / lsum[i];
  }
}

__global__ __launch_bounds__(512) void final_kernel(
    const float* __restrict__ vws, const int* __restrict__ mask,
    float* __restrict__ out) {
  const int b = blockIdx.x, l = threadIdx.x;  // grid 32, block 512
  __shared__ float redm[8], reds[8];
  float v = 0.f;
#pragma unroll
  for (int h = 0; h < 8; ++h) v += vws[(size_t)(b * 8 + h) * 512 + l];
  if (mask[b * 512 + l] == 0) v = NEG;
  float mx = v;
#pragma unroll
  for (int off = 32; off >= 1; off >>= 1) mx = fmaxf(mx, __shfl_xor(mx, off));
  if ((l & 63) == 0) redm[l >> 6] = mx;
  __syncthreads();
  float M = redm[0];
#pragma unroll
  for (int i = 1; i < 8; ++i) M = fmaxf(M, redm[i]);
  const float e = __expf(v - M);
  float sm = e;
#pragma unroll
  for (int off = 32; off >= 1; off >>= 1) sm += __shfl_xor(sm, off);
  if ((l & 63) == 0) reds[l >> 6] = sm;
  __syncthreads();
  float S = 0.f;
#pragma unroll
  for (int i = 0; i < 8; ++i) S += reds[i];
  out[b * 512 + l] = e / S;
}

extern "C" void kernel_launch(void* const* d_in, const int* in_sizes, int n_in,
                              void* d_out, int out_size, void* d_ws, size_t ws_size,
                              hipStream_t stream) {
  const float* X  = (const float*)d_in[0];
  const int*  mk  = (const int*)d_in[1];   // bool mask as int32 (see header note)
  const float* W1 = (const float*)d_in[2];
  const float* W2 = (const float*)d_in[3];
  const float* W3 = (const float*)d_in[4];
  const float* w  = (const float*)d_in[5];
  float* out = (float*)d_out;

  float* u   = (float*)d_ws;                       // 1024 floats
  float* Y   = u + 1024;                           // 16384*520 floats
  float* vws = Y + (size_t)16384 * YC;             // 32*8*512 floats

  fold_w_kernel<<<dim3(8), dim3(128), 0, stream>>>(W3, w, u);
  proj_kernel<<<dim3(256, 9), dim3(256), 0, stream>>>(X, W1, W2, u, Y);
  attn_kernel<<<dim3(8, 8, 32), dim3(256), 0, stream>>>(Y, mk, vws);
  final_kernel<<<dim3(32), dim3(512), 0, stream>>>(vws, mk, out);
}

// Round 2
// 61.228 us; speedup vs baseline: 2.2829x; 2.2829x over previous
//
#include <hip/hip_runtime.h>
#include <hip/hip_bf16.h>

// AttentionNTKChoiceModel — MFMA bf16-split version.
// B=32, L=512, D=128, H=8, D0=D2=32.
// proj:  Y = X @ [W1;W2;u]^T via mfma_f32_16x16x32_bf16, 3-term hi/lo split
//        (hh + hl + lh), emits Qhi/Qlo (pre-scaled by 1/sqrt(32)*log2(e)),
//        Khi/Klo, Vw (f32, w folded: u_h = sum_d w[h,d] W3[h*32+d,:]/sqrt(8)).
// attn:  per (b,h,256q-block): scores^T = K @ Q^T (swapped so key-reduction is
//        lane-local), online softmax in exp2 domain, val += p*Vw.
// final: sum heads, q-mask, 512-wide softmax per batch row.
//
// ws layout: u f32[1024] | Qhi,Qlo,Khi,Klo bf16[16384*256] | Vw f32[16384*8]
//            | vws f32[32*8*512]

typedef __attribute__((ext_vector_type(8))) short bf16x8;
typedef __attribute__((ext_vector_type(4))) float f32x4;
typedef __attribute__((ext_vector_type(8))) unsigned short ushort8;

#define NEG (-10000.0f)
#define LOG2E 1.4426950408889634f
#define QSCALE (0.17677669529663687f * LOG2E)

__device__ __forceinline__ unsigned short bf16_rn(float x, float* rep) {
  unsigned u = __float_as_uint(x);
  unsigned r = (u + 0x7FFFu + ((u >> 16) & 1u)) >> 16;
  *rep = __uint_as_float(r << 16);
  return (unsigned short)r;
}

__global__ void fold_w_kernel(const float* __restrict__ W3,
                              const float* __restrict__ w,
                              float* __restrict__ u) {
  const int h = blockIdx.x, k = threadIdx.x;  // grid 8, block 128
  float acc = 0.f;
#pragma unroll
  for (int d = 0; d < 32; ++d)
    acc += W3[(h * 32 + d) * 128 + k] * w[h * 32 + d];
  u[h * 128 + k] = acc * 0.3535533905932738f;  // includes 1/sqrt(8)
}

// C[16384, 520] = X[16384,128] @ Wcat^T, MFMA 3-term bf16 split.
// Block: 256 thr (4 waves), tile 64Mx64N, K chunks of 64.
__global__ __launch_bounds__(256) void proj_kernel(
    const float* __restrict__ X, const float* __restrict__ W1,
    const float* __restrict__ W2, const float* __restrict__ u,
    unsigned short* __restrict__ Qhi, unsigned short* __restrict__ Qlo,
    unsigned short* __restrict__ Khi, unsigned short* __restrict__ Klo,
    float* __restrict__ Vw) {
  // pad 8: row stride 72 ushort = 144B = 36 dwords (36%8==4 -> bank-balanced,
  // 144%16==0 -> b128-aligned)
  __shared__ unsigned short Xh[64][72], Xl[64][72], Wh[64][72], Wl[64][72];
  const int t = threadIdx.x;
  const int row0 = blockIdx.x * 64, col0 = blockIdx.y * 64;
  const int w = t >> 6, lane = t & 63, g = lane >> 4, r16 = lane & 15;
  const int srow = t >> 2, seg = t & 3;  // stage: row 0..63, 16-float segment
  const int wj = col0 + srow;
  const float* wsrc = nullptr;
  if (wj < 256)      wsrc = W1 + (size_t)wj * 128;
  else if (wj < 512) wsrc = W2 + (size_t)(wj - 256) * 128;
  else if (wj < 520) wsrc = u + (size_t)(wj - 512) * 128;

  f32x4 acc[4];
#pragma unroll
  for (int n = 0; n < 4; ++n) acc[n] = (f32x4){0.f, 0.f, 0.f, 0.f};

  for (int kc = 0; kc < 128; kc += 64) {
    if (kc) __syncthreads();  // protect previous chunk reads
    {
      float xv[16];
      const float4* xs = (const float4*)(X + (size_t)(row0 + srow) * 128 + kc + seg * 16);
#pragma unroll
      for (int i = 0; i < 4; ++i) {
        float4 v = xs[i];
        xv[4 * i] = v.x; xv[4 * i + 1] = v.y; xv[4 * i + 2] = v.z; xv[4 * i + 3] = v.w;
      }
      ushort8 hA, hB, lA, lB;
#pragma unroll
      for (int i = 0; i < 8; ++i) {
        float hf, lf;
        hA[i] = (short)bf16_rn(xv[i], &hf);
        lA[i] = (short)bf16_rn(xv[i] - hf, &lf);
      }
#pragma unroll
      for (int i = 0; i < 8; ++i) {
        float hf, lf;
        hB[i] = (short)bf16_rn(xv[8 + i], &hf);
        lB[i] = (short)bf16_rn(xv[8 + i] - hf, &lf);
      }
      *(ushort8*)&Xh[srow][seg * 16]     = hA;
      *(ushort8*)&Xh[srow][seg * 16 + 8] = hB;
      *(ushort8*)&Xl[srow][seg * 16]     = lA;
      *(ushort8*)&Xl[srow][seg * 16 + 8] = lB;

      float wv[16];
      if (wsrc) {
        const float4* ws = (const float4*)(wsrc + kc + seg * 16);
#pragma unroll
        for (int i = 0; i < 4; ++i) {
          float4 v = ws[i];
          wv[4 * i] = v.x; wv[4 * i + 1] = v.y; wv[4 * i + 2] = v.z; wv[4 * i + 3] = v.w;
        }
      } else {
#pragma unroll
        for (int i = 0; i < 16; ++i) wv[i] = 0.f;
      }
#pragma unroll
      for (int i = 0; i < 8; ++i) {
        float hf, lf;
        hA[i] = (short)bf16_rn(wv[i], &hf);
        lA[i] = (short)bf16_rn(wv[i] - hf, &lf);
      }
#pragma unroll
      for (int i = 0; i < 8; ++i) {
        float hf, lf;
        hB[i] = (short)bf16_rn(wv[8 + i], &hf);
        lB[i] = (short)bf16_rn(wv[8 + i] - hf, &lf);
      }
      *(ushort8*)&Wh[srow][seg * 16]     = hA;
      *(ushort8*)&Wh[srow][seg * 16 + 8] = hB;
      *(ushort8*)&Wl[srow][seg * 16]     = lA;
      *(ushort8*)&Wl[srow][seg * 16 + 8] = lB;
    }
    __syncthreads();
#pragma unroll
    for (int ks = 0; ks < 2; ++ks) {
      bf16x8 ah = *(const bf16x8*)&Xh[w * 16 + r16][ks * 32 + g * 8];
      bf16x8 al = *(const bf16x8*)&Xl[w * 16 + r16][ks * 32 + g * 8];
#pragma unroll
      for (int n = 0; n < 4; ++n) {
        bf16x8 bh = *(const bf16x8*)&Wh[n * 16 + r16][ks * 32 + g * 8];
        bf16x8 bl = *(const bf16x8*)&Wl[n * 16 + r16][ks * 32 + g * 8];
        acc[n] = __builtin_amdgcn_mfma_f32_16x16x32_bf16(ah, bh, acc[n], 0, 0, 0);
        acc[n] = __builtin_amdgcn_mfma_f32_16x16x32_bf16(ah, bl, acc[n], 0, 0, 0);
        acc[n] = __builtin_amdgcn_mfma_f32_16x16x32_bf16(al, bh, acc[n], 0, 0, 0);
      }
    }
  }
  // epilogue: C row=(lane>>4)*4+reg, col=lane&15 (m89-verified layout)
#pragma unroll
  for (int n = 0; n < 4; ++n) {
    const int col = col0 + n * 16 + r16;
#pragma unroll
    for (int r = 0; r < 4; ++r) {
      const int row = row0 + w * 16 + g * 4 + r;
      const float val = acc[n][r];
      if (col < 256) {
        const float sv = val * QSCALE;
        float hf, lf;
        const unsigned short hb = bf16_rn(sv, &hf);
        const unsigned short lb = bf16_rn(sv - hf, &lf);
        Qhi[(size_t)row * 256 + col] = hb;
        Qlo[(size_t)row * 256 + col] = lb;
      } else if (col < 512) {
        float hf, lf;
        const unsigned short hb = bf16_rn(val, &hf);
        const unsigned short lb = bf16_rn(val - hf, &lf);
        Khi[(size_t)row * 256 + (col - 256)] = hb;
        Klo[(size_t)row * 256 + (col - 256)] = lb;
      } else if (col < 520) {
        Vw[(size_t)row * 8 + (col - 512)] = val;
      }
    }
  }
}

// Block: (qhalf, h, b), 512 thr (8 waves). Wave w owns 32 q rows (2 qtiles).
// K chunks of 64 keys, double-buffered LDS, T14 issue-early/write-late.
__global__ __launch_bounds__(512) void attn_kernel(
    const unsigned short* __restrict__ Qhi, const unsigned short* __restrict__ Qlo,
    const unsigned short* __restrict__ Khi, const unsigned short* __restrict__ Klo,
    const float* __restrict__ Vw, const int* __restrict__ mask,
    float* __restrict__ vws) {
  // pad to 40 ushort = 80B = 20 dwords (20%8==4 balanced, 80%16==0 aligned)
  __shared__ unsigned short KhS[2][64][40], KlS[2][64][40];
  __shared__ float VwS[2][64], biasS[2][64];
  const int t = threadIdx.x;
  const int w = t >> 6, lane = t & 63, g = lane >> 4, r16 = lane & 15;
  const int qbase = blockIdx.x * 256, h = blockIdx.y, b = blockIdx.z;

  bf16x8 qh[2], ql[2];
#pragma unroll
  for (int qt = 0; qt < 2; ++qt) {
    const size_t off =
        (size_t)(b * 512 + qbase + w * 32 + qt * 16 + r16) * 256 + h * 32 + g * 8;
    qh[qt] = *(const bf16x8*)&Qhi[off];
    ql[qt] = *(const bf16x8*)&Qlo[off];
  }

  const int srow = (t & 255) >> 2, seg = t & 3;
  ushort8 kreg = {};
  float vreg = 0.f, breg = 0.f;

  float m[2] = {-1e30f, -1e30f}, lsum[2] = {0.f, 0.f}, val[2] = {0.f, 0.f};

#define LOAD_CH(c)                                                              \
  {                                                                             \
    const size_t roff = (size_t)(b * 512 + (c) * 64 + srow) * 256 + h * 32 + seg * 8; \
    kreg = (t < 256) ? *(const ushort8*)&Khi[roff] : *(const ushort8*)&Klo[roff];     \
    if (t < 64) vreg = Vw[(size_t)(b * 512 + (c) * 64 + t) * 8 + h];            \
    else if (t < 128) breg = mask[b * 512 + (c) * 64 + (t - 64)] ? 0.f : NEG * LOG2E; \
  }
#define WRITE_CH(c)                                                             \
  {                                                                             \
    const int bfi = (c) & 1;                                                    \
    if (t < 256) *(ushort8*)&KhS[bfi][srow][seg * 8] = kreg;                    \
    else *(ushort8*)&KlS[bfi][srow][seg * 8] = kreg;                            \
    if (t < 64) VwS[bfi][t] = vreg;                                             \
    else if (t < 128) biasS[bfi][t - 64] = breg;                                \
  }

  LOAD_CH(0);
  WRITE_CH(0);
  __syncthreads();

  for (int c = 0; c < 8; ++c) {
    if (c < 7) LOAD_CH(c + 1);  // HBM latency hides under compute
    const int bfi = c & 1;
    bf16x8 ah[4], al[4];
#pragma unroll
    for (int j = 0; j < 4; ++j) {
      ah[j] = *(const bf16x8*)&KhS[bfi][j * 16 + r16][g * 8];
      al[j] = *(const bf16x8*)&KlS[bfi][j * 16 + r16][g * 8];
    }
    f32x4 sc[4][2];
#pragma unroll
    for (int j = 0; j < 4; ++j)
#pragma unroll
      for (int qt = 0; qt < 2; ++qt) {
        f32x4 z = (f32x4){0.f, 0.f, 0.f, 0.f};
        z = __builtin_amdgcn_mfma_f32_16x16x32_bf16(ah[j], qh[qt], z, 0, 0, 0);
        z = __builtin_amdgcn_mfma_f32_16x16x32_bf16(ah[j], ql[qt], z, 0, 0, 0);
        z = __builtin_amdgcn_mfma_f32_16x16x32_bf16(al[j], qh[qt], z, 0, 0, 0);
        sc[j][qt] = z;
      }
    float4 bs[4], vw4[4];
#pragma unroll
    for (int j = 0; j < 4; ++j) {
      bs[j]  = *(const float4*)&biasS[bfi][j * 16 + g * 4];
      vw4[j] = *(const float4*)&VwS[bfi][j * 16 + g * 4];
    }
#pragma unroll
    for (int qt = 0; qt < 2; ++qt) {
      float sb[4][4];
      float cmax = -1e30f;
#pragma unroll
      for (int j = 0; j < 4; ++j) {
        sb[j][0] = sc[j][qt][0] + bs[j].x;
        sb[j][1] = sc[j][qt][1] + bs[j].y;
        sb[j][2] = sc[j][qt][2] + bs[j].z;
        sb[j][3] = sc[j][qt][3] + bs[j].w;
#pragma unroll
        for (int r = 0; r < 4; ++r) cmax = fmaxf(cmax, sb[j][r]);
      }
      cmax = fmaxf(cmax, __shfl_xor(cmax, 16));
      cmax = fmaxf(cmax, __shfl_xor(cmax, 32));
      const float mnew = fmaxf(m[qt], cmax);
      const float f = __builtin_amdgcn_exp2f(m[qt] - mnew);
      m[qt] = mnew;
      float ls = lsum[qt] * f, vv = val[qt] * f;
#pragma unroll
      for (int j = 0; j < 4; ++j) {
        const float p0 = __builtin_amdgcn_exp2f(sb[j][0] - mnew);
        const float p1 = __builtin_amdgcn_exp2f(sb[j][1] - mnew);
        const float p2 = __builtin_amdgcn_exp2f(sb[j][2] - mnew);
        const float p3 = __builtin_amdgcn_exp2f(sb[j][3] - mnew);
        ls += (p0 + p1) + (p2 + p3);
        vv = fmaf(p0, vw4[j].x, vv);
        vv = fmaf(p1, vw4[j].y, vv);
        vv = fmaf(p2, vw4[j].z, vv);
        vv = fmaf(p3, vw4[j].w, vv);
      }
      lsum[qt] = ls; val[qt] = vv;
    }
    __syncthreads();
    if (c < 7) {
      WRITE_CH(c + 1);
      __syncthreads();
    }
  }
#pragma unroll
  for (int qt = 0; qt < 2; ++qt) {
    lsum[qt] += __shfl_xor(lsum[qt], 16);
    val[qt]  += __shfl_xor(val[qt], 16);
    lsum[qt] += __shfl_xor(lsum[qt], 32);
    val[qt]  += __shfl_xor(val[qt], 32);
  }
  if (lane < 16) {
#pragma unroll
    for (int qt = 0; qt < 2; ++qt)
      vws[(size_t)(b * 8 + h) * 512 + qbase + w * 32 + qt * 16 + lane] =
          val[qt] / lsum[qt];
  }
#undef LOAD_CH
#undef WRITE_CH
}

__global__ __launch_bounds__(512) void final_kernel(
    const float* __restrict__ vws, const int* __restrict__ mask,
    float* __restrict__ out) {
  const int b = blockIdx.x, l = threadIdx.x;  // grid 32, block 512
  __shared__ float redm[8], reds[8];
  float v = 0.f;
#pragma unroll
  for (int h = 0; h < 8; ++h) v += vws[(size_t)(b * 8 + h) * 512 + l];
  if (mask[b * 512 + l] == 0) v = NEG;
  float mx = v;
#pragma unroll
  for (int off = 32; off >= 1; off >>= 1) mx = fmaxf(mx, __shfl_xor(mx, off));
  if ((l & 63) == 0) redm[l >> 6] = mx;
  __syncthreads();
  float M = redm[0];
#pragma unroll
  for (int i = 1; i < 8; ++i) M = fmaxf(M, redm[i]);
  const float e = __expf(v - M);
  float sm = e;
#pragma unroll
  for (int off = 32; off >= 1; off >>= 1) sm += __shfl_xor(sm, off);
  if ((l & 63) == 0) reds[l >> 6] = sm;
  __syncthreads();
  float S = 0.f;
#pragma unroll
  for (int i = 0; i < 8; ++i) S += reds[i];
  out[b * 512 + l] = e / S;
}

extern "C" void kernel_launch(void* const* d_in, const int* in_sizes, int n_in,
                              void* d_out, int out_size, void* d_ws, size_t ws_size,
                              hipStream_t stream) {
  const float* X  = (const float*)d_in[0];
  const int*  mk  = (const int*)d_in[1];
  const float* W1 = (const float*)d_in[2];
  const float* W2 = (const float*)d_in[3];
  const float* W3 = (const float*)d_in[4];
  const float* w  = (const float*)d_in[5];
  float* out = (float*)d_out;

  char* ws = (char*)d_ws;
  float* u   = (float*)ws;                                  //   4,096 B
  unsigned short* Qhi = (unsigned short*)(ws + 4096);       //   8 MB each
  unsigned short* Qlo = Qhi + (size_t)16384 * 256;
  unsigned short* Khi = Qlo + (size_t)16384 * 256;
  unsigned short* Klo = Khi + (size_t)16384 * 256;
  float* Vw  = (float*)(Klo + (size_t)16384 * 256);         // 512 KB
  float* vws = Vw + (size_t)16384 * 8;                      // 512 KB

  fold_w_kernel<<<dim3(8), dim3(128), 0, stream>>>(W3, w, u);
  proj_kernel<<<dim3(256, 9), dim3(256), 0, stream>>>(X, W1, W2, u,
                                                      Qhi, Qlo, Khi, Klo, Vw);
  attn_kernel<<<dim3(2, 8, 32), dim3(512), 0, stream>>>(Qhi, Qlo, Khi, Klo,
                                                        Vw, mk, vws);
  final_kernel<<<dim3(32), dim3(512), 0, stream>>>(vws, mk, out);
}

// Round 4
// 60.255 us; speedup vs baseline: 2.3197x; 1.0161x over previous
//
#include <hip/hip_runtime.h>
#include <hip/hip_bf16.h>

// AttentionNTKChoiceModel — MFMA bf16-split, corrected 4-term proj.
// B=32, L=512, D=128, H=8, D0=D2=32.
//
// convert: X[16384,128]f32 -> X2[16384,256]bf16  (cols 0..127 hi, 128..255 lo)
//          Wc[576,256]bf16: rows W1(0..255), W2(256..511), u(512..519), 0-pad
//          u_h = sum_d w[h,d]*W3[h*32+d,:]/sqrt(8)
// proj:    acc = X2 . Wc[diag chunk] + X2 . Wc[chunk+128 mod 256]
//          (diag = hh+ll, shifted = hl+lh -> exact f32 product).
//          Epilogue re-splits into per-head Q2/K2 [B,H,L,64]bf16
//          (d 0..31 hi, 32..63 lo; Q pre-scaled 1/sqrt(32)*log2e), Vw[B,H,L]f32.
// attn:    per (b,h,256q): scores^T = K @ Q^T 3-term (hh+hl+lh), online
//          softmax in exp2 domain, val += p*Vw -> vws[B,H,L]
// final:   sum heads, q-mask, 512-wide softmax per batch row.

typedef __attribute__((ext_vector_type(8))) short bf16x8;
typedef __attribute__((ext_vector_type(4))) float f32x4;
typedef __attribute__((ext_vector_type(8))) unsigned short ushort8;
typedef __attribute__((ext_vector_type(4))) unsigned short ushort4v;

#define NEG (-10000.0f)
#define LOG2E 1.4426950408889634f
#define QSCALE (0.17677669529663687f * LOG2E)

__device__ __forceinline__ unsigned short bf16_rn(float x, float* rep) {
  unsigned u = __float_as_uint(x);
  unsigned r = (u + 0x7FFFu + ((u >> 16) & 1u)) >> 16;
  *rep = __uint_as_float(r << 16);
  return (unsigned short)r;
}

// grid 1057 x 256: [0,1024) X-split, [1024,1056) W1/W2-split, 1056 u+pad
__global__ __launch_bounds__(256) void convert_kernel(
    const float* __restrict__ X, const float* __restrict__ W1,
    const float* __restrict__ W2, const float* __restrict__ W3,
    const float* __restrict__ w,
    unsigned short* __restrict__ X2, unsigned short* __restrict__ Wc) {
  const int bx = blockIdx.x, t = threadIdx.x;
  if (bx < 1056) {
    const float* src;
    unsigned short* dst;
    int row, c;
    if (bx < 1024) {
      const size_t flat = (size_t)bx * 2048 + t * 8;
      row = (int)(flat >> 7); c = (int)(flat & 127);
      src = &X[flat];
      dst = &X2[(size_t)row * 256 + c];
    } else {
      const int flat = (bx - 1024) * 2048 + t * 8;
      row = flat >> 7; c = flat & 127;
      src = (row < 256) ? &W1[(size_t)row * 128 + c]
                        : &W2[(size_t)(row - 256) * 128 + c];
      dst = &Wc[(size_t)row * 256 + c];
    }
    float xv[8];
    *(float4*)&xv[0] = *(const float4*)src;
    *(float4*)&xv[4] = *(const float4*)(src + 4);
    ushort8 hi, lo;
#pragma unroll
    for (int i = 0; i < 8; ++i) {
      float hf, lf;
      hi[i] = bf16_rn(xv[i], &hf);
      lo[i] = bf16_rn(xv[i] - hf, &lf);
    }
    *(ushort8*)dst = hi;
    *(ushort8*)(dst + 128) = lo;
  } else {
    __shared__ float uS[8][128];
    if (t < 128) {
#pragma unroll
      for (int h = 0; h < 8; ++h) {
        float acc = 0.f;
#pragma unroll
        for (int d = 0; d < 32; ++d)
          acc += W3[(h * 32 + d) * 128 + t] * w[h * 32 + d];
        uS[h][t] = acc * 0.3535533905932738f;  // 1/sqrt(8)
      }
    }
    __syncthreads();
    {
      const int r = t >> 5, c = (t & 31) * 4;
      float4 v = *(float4*)&uS[r][c];
      float vv[4] = {v.x, v.y, v.z, v.w};
      ushort4v hi, lo;
#pragma unroll
      for (int i = 0; i < 4; ++i) {
        float hf, lf;
        hi[i] = bf16_rn(vv[i], &hf);
        lo[i] = bf16_rn(vv[i] - hf, &lf);
      }
      *(ushort4v*)&Wc[(size_t)(512 + r) * 256 + c] = hi;
      *(ushort4v*)&Wc[(size_t)(512 + r) * 256 + 128 + c] = lo;
    }
    const ushort8 z = {};
    for (int i = t; i < 1792; i += 256)  // zero rows 520..575
      *(ushort8*)&Wc[(size_t)520 * 256 + i * 8] = z;
  }
}

// [16384,576] GEMM, exact 4-term: diag (hh+ll) + shifted (hl+lh).
// Block 256thr (4 waves), tile 64x64, K chunks of 64 over the 256-wide [hi|lo].
__global__ __launch_bounds__(256) void proj_kernel(
    const unsigned short* __restrict__ X2, const unsigned short* __restrict__ Wc,
    unsigned short* __restrict__ Q2, unsigned short* __restrict__ K2,
    float* __restrict__ Vw) {
  // stride 72 ushort = 144B (36 dw, %8==4 -> 2-way max on frag reads)
  __shared__ unsigned short XS[64][72], WSd[64][72], WSx[64][72];
  const int t = threadIdx.x;
  const int row0 = blockIdx.x * 64, col0 = blockIdx.y * 64;
  const int w = t >> 6, lane = t & 63, g = lane >> 4, r16 = lane & 15;
  const int srow = t >> 2, su = (t & 3) * 16;

  f32x4 acc[4];
#pragma unroll
  for (int n = 0; n < 4; ++n) acc[n] = (f32x4){0.f, 0.f, 0.f, 0.f};

  for (int kc = 0; kc < 256; kc += 64) {
    const int kcx = (kc + 128) & 255;
    if (kc) __syncthreads();
    {
      const size_t xo = (size_t)(row0 + srow) * 256 + kc + su;
      const size_t wd = (size_t)(col0 + srow) * 256 + kc + su;
      const size_t wx = (size_t)(col0 + srow) * 256 + kcx + su;
      ushort8 a = *(const ushort8*)&X2[xo];
      ushort8 b = *(const ushort8*)&X2[xo + 8];
      ushort8 c = *(const ushort8*)&Wc[wd];
      ushort8 d = *(const ushort8*)&Wc[wd + 8];
      ushort8 e = *(const ushort8*)&Wc[wx];
      ushort8 f = *(const ushort8*)&Wc[wx + 8];
      *(ushort8*)&XS[srow][su] = a;
      *(ushort8*)&XS[srow][su + 8] = b;
      *(ushort8*)&WSd[srow][su] = c;
      *(ushort8*)&WSd[srow][su + 8] = d;
      *(ushort8*)&WSx[srow][su] = e;
      *(ushort8*)&WSx[srow][su + 8] = f;
    }
    __syncthreads();
#pragma unroll
    for (int ks = 0; ks < 2; ++ks) {
      bf16x8 ah = *(const bf16x8*)&XS[w * 16 + r16][ks * 32 + g * 8];
#pragma unroll
      for (int n = 0; n < 4; ++n) {
        bf16x8 bd = *(const bf16x8*)&WSd[n * 16 + r16][ks * 32 + g * 8];
        bf16x8 bx = *(const bf16x8*)&WSx[n * 16 + r16][ks * 32 + g * 8];
        acc[n] = __builtin_amdgcn_mfma_f32_16x16x32_bf16(ah, bd, acc[n], 0, 0, 0);
        acc[n] = __builtin_amdgcn_mfma_f32_16x16x32_bf16(ah, bx, acc[n], 0, 0, 0);
      }
    }
  }
  // C layout: row = w*16 + g*4 + r, col = col0 + n*16 + r16 (verified r2)
#pragma unroll
  for (int n = 0; n < 4; ++n) {
    const int col = col0 + n * 16 + r16;
#pragma unroll
    for (int r = 0; r < 4; ++r) {
      const int row = row0 + w * 16 + g * 4 + r;
      const int b = row >> 9, l = row & 511;
      const float val = acc[n][r];
      if (col < 256) {
        const float sv = val * QSCALE;
        float hf, lf;
        const unsigned short hb = bf16_rn(sv, &hf);
        const unsigned short lb = bf16_rn(sv - hf, &lf);
        const size_t o = ((size_t)(b * 8 + (col >> 5)) * 512 + l) * 64 + (col & 31);
        Q2[o] = hb; Q2[o + 32] = lb;
      } else if (col < 512) {
        const int c2 = col - 256;
        float hf, lf;
        const unsigned short hb = bf16_rn(val, &hf);
        const unsigned short lb = bf16_rn(val - hf, &lf);
        const size_t o = ((size_t)(b * 8 + (c2 >> 5)) * 512 + l) * 64 + (c2 & 31);
        K2[o] = hb; K2[o + 32] = lb;
      } else if (col < 520) {
        Vw[(size_t)(b * 8 + (col - 512)) * 512 + l] = val;
      }
    }
  }
}

// Block (qhalf, h, b), 512 thr. Wave w owns 32 q rows. 64-key chunks, dbuf.
__global__ __launch_bounds__(512) void attn_kernel(
    const unsigned short* __restrict__ Q2, const unsigned short* __restrict__ K2,
    const float* __restrict__ Vw, const int* __restrict__ mask,
    float* __restrict__ vws) {
  __shared__ unsigned short KS[2][64][72];
  __shared__ float VwS[2][64], biasS[2][64];
  const int t = threadIdx.x;
  const int w = t >> 6, lane = t & 63, g = lane >> 4, r16 = lane & 15;
  const int qbase = blockIdx.x * 256, h = blockIdx.y, b = blockIdx.z;
  const size_t headoff = (size_t)(b * 8 + h) * 512;

  bf16x8 qf[2][2];  // [qtile][hi/lo]
#pragma unroll
  for (int qt = 0; qt < 2; ++qt)
#pragma unroll
    for (int ks = 0; ks < 2; ++ks)
      qf[qt][ks] = *(const bf16x8*)
          &Q2[(headoff + qbase + w * 32 + qt * 16 + r16) * 64 + ks * 32 + g * 8];

  const int srow = t >> 3, su = (t & 7) * 8;
  ushort8 kreg = {};
  float vreg = 0.f, breg = 0.f;
  float m[2] = {-1e30f, -1e30f}, lsum[2] = {0.f, 0.f}, val[2] = {0.f, 0.f};

#define LOAD_CH(c)                                                        \
  {                                                                       \
    kreg = *(const ushort8*)&K2[(headoff + (c) * 64 + srow) * 64 + su];   \
    if (t < 64) vreg = Vw[headoff + (c) * 64 + t];                        \
    else if (t < 128)                                                     \
      breg = mask[b * 512 + (c) * 64 + (t - 64)] ? 0.f : NEG * LOG2E;     \
  }
#define WRITE_CH(c)                                                       \
  {                                                                       \
    const int bfi = (c) & 1;                                              \
    *(ushort8*)&KS[bfi][srow][su] = kreg;                                 \
    if (t < 64) VwS[bfi][t] = vreg;                                       \
    else if (t < 128) biasS[bfi][t - 64] = breg;                          \
  }

  LOAD_CH(0);
  WRITE_CH(0);
  __syncthreads();

  for (int c = 0; c < 8; ++c) {
    if (c < 7) LOAD_CH(c + 1);  // HBM latency hides under compute
    const int bfi = c & 1;
    bf16x8 a0[4], a1[4];  // K hi / K lo for 4 key-subtiles
#pragma unroll
    for (int j = 0; j < 4; ++j) {
      a0[j] = *(const bf16x8*)&KS[bfi][j * 16 + r16][g * 8];
      a1[j] = *(const bf16x8*)&KS[bfi][j * 16 + r16][32 + g * 8];
    }
    f32x4 sc[4][2];
#pragma unroll
    for (int j = 0; j < 4; ++j)
#pragma unroll
      for (int qt = 0; qt < 2; ++qt) {
        f32x4 z = (f32x4){0.f, 0.f, 0.f, 0.f};
        z = __builtin_amdgcn_mfma_f32_16x16x32_bf16(a0[j], qf[qt][0], z, 0, 0, 0);
        z = __builtin_amdgcn_mfma_f32_16x16x32_bf16(a0[j], qf[qt][1], z, 0, 0, 0);
        z = __builtin_amdgcn_mfma_f32_16x16x32_bf16(a1[j], qf[qt][0], z, 0, 0, 0);
        sc[j][qt] = z;
      }
    float4 bs[4], vw4[4];
#pragma unroll
    for (int j = 0; j < 4; ++j) {
      bs[j]  = *(const float4*)&biasS[bfi][j * 16 + g * 4];
      vw4[j] = *(const float4*)&VwS[bfi][j * 16 + g * 4];
    }
#pragma unroll
    for (int qt = 0; qt < 2; ++qt) {
      float sb[4][4];
      float cmax = -1e30f;
#pragma unroll
      for (int j = 0; j < 4; ++j) {
        sb[j][0] = sc[j][qt][0] + bs[j].x;
        sb[j][1] = sc[j][qt][1] + bs[j].y;
        sb[j][2] = sc[j][qt][2] + bs[j].z;
        sb[j][3] = sc[j][qt][3] + bs[j].w;
#pragma unroll
        for (int r = 0; r < 4; ++r) cmax = fmaxf(cmax, sb[j][r]);
      }
      cmax = fmaxf(cmax, __shfl_xor(cmax, 16));
      cmax = fmaxf(cmax, __shfl_xor(cmax, 32));
      const float mnew = fmaxf(m[qt], cmax);
      const float f = __builtin_amdgcn_exp2f(m[qt] - mnew);
      m[qt] = mnew;
      float ls = lsum[qt] * f, vv = val[qt] * f;
#pragma unroll
      for (int j = 0; j < 4; ++j) {
        const float p0 = __builtin_amdgcn_exp2f(sb[j][0] - mnew);
        const float p1 = __builtin_amdgcn_exp2f(sb[j][1] - mnew);
        const float p2 = __builtin_amdgcn_exp2f(sb[j][2] - mnew);
        const float p3 = __builtin_amdgcn_exp2f(sb[j][3] - mnew);
        ls += (p0 + p1) + (p2 + p3);
        vv = fmaf(p0, vw4[j].x, vv);
        vv = fmaf(p1, vw4[j].y, vv);
        vv = fmaf(p2, vw4[j].z, vv);
        vv = fmaf(p3, vw4[j].w, vv);
      }
      lsum[qt] = ls; val[qt] = vv;
    }
    __syncthreads();
    if (c < 7) {
      WRITE_CH(c + 1);
      __syncthreads();
    }
  }
#pragma unroll
  for (int qt = 0; qt < 2; ++qt) {
    lsum[qt] += __shfl_xor(lsum[qt], 16);
    val[qt]  += __shfl_xor(val[qt], 16);
    lsum[qt] += __shfl_xor(lsum[qt], 32);
    val[qt]  += __shfl_xor(val[qt], 32);
  }
  if (lane < 16) {
#pragma unroll
    for (int qt = 0; qt < 2; ++qt)
      vws[headoff + qbase + w * 32 + qt * 16 + lane] = val[qt] / lsum[qt];
  }
#undef LOAD_CH
#undef WRITE_CH
}

__global__ __launch_bounds__(512) void final_kernel(
    const float* __restrict__ vws, const int* __restrict__ mask,
    float* __restrict__ out) {
  const int b = blockIdx.x, l = threadIdx.x;  // grid 32, block 512
  __shared__ float redm[8], reds[8];
  float v = 0.f;
#pragma unroll
  for (int h = 0; h < 8; ++h) v += vws[(size_t)(b * 8 + h) * 512 + l];
  if (mask[b * 512 + l] == 0) v = NEG;
  float mx = v;
#pragma unroll
  for (int off = 32; off >= 1; off >>= 1) mx = fmaxf(mx, __shfl_xor(mx, off));
  if ((l & 63) == 0) redm[l >> 6] = mx;
  __syncthreads();
  float M = redm[0];
#pragma unroll
  for (int i = 1; i < 8; ++i) M = fmaxf(M, redm[i]);
  const float e = __expf(v - M);
  float sm = e;
#pragma unroll
  for (int off = 32; off >= 1; off >>= 1) sm += __shfl_xor(sm, off);
  if ((l & 63) == 0) reds[l >> 6] = sm;
  __syncthreads();
  float S = 0.f;
#pragma unroll
  for (int i = 0; i < 8; ++i) S += reds[i];
  out[b * 512 + l] = e / S;
}

extern "C" void kernel_launch(void* const* d_in, const int* in_sizes, int n_in,
                              void* d_out, int out_size, void* d_ws, size_t ws_size,
                              hipStream_t stream) {
  const float* X  = (const float*)d_in[0];
  const int*  mk  = (const int*)d_in[1];
  const float* W1 = (const float*)d_in[2];
  const float* W2 = (const float*)d_in[3];
  const float* W3 = (const float*)d_in[4];
  const float* w  = (const float*)d_in[5];
  float* out = (float*)d_out;

  char* ws = (char*)d_ws;
  unsigned short* X2 = (unsigned short*)ws;                 // 16384*256  = 8 MB
  unsigned short* Wc = X2 + (size_t)16384 * 256;            //   576*256  = 288 KB
  unsigned short* Q2 = Wc + (size_t)576 * 256;              // 32*8*512*64 = 16 MB
  unsigned short* K2 = Q2 + (size_t)32 * 8 * 512 * 64;      // 16 MB
  float* Vw  = (float*)(K2 + (size_t)32 * 8 * 512 * 64);    // 512 KB
  float* vws = Vw + (size_t)32 * 8 * 512;                   // 512 KB

  convert_kernel<<<dim3(1057), dim3(256), 0, stream>>>(X, W1, W2, W3, w, X2, Wc);
  proj_kernel<<<dim3(256, 9), dim3(256), 0, stream>>>(X2, Wc, Q2, K2, Vw);
  attn_kernel<<<dim3(2, 8, 32), dim3(512), 0, stream>>>(Q2, K2, Vw, mk, vws);
  final_kernel<<<dim3(32), dim3(512), 0, stream>>>(vws, mk, out);
}